// Round 1
// baseline (5157.791 us; speedup 1.0000x reference)
//
#include <hip/hip_runtime.h>
#include <hip/hip_bf16.h>
#include <stdint.h>

#define M_DIM 2048
#define N_DIM 25000
#define K_DIM 32000
#define N_PAD 25088            // 196 * 128
#define BM 128
#define BN 128
#define BK 64
#define NTM (M_DIM / BM)       // 16
#define NTN (N_PAD / BN)       // 196
#define NWG (NTM * NTN)        // 3136

typedef __attribute__((ext_vector_type(8))) short short8;
typedef __attribute__((ext_vector_type(4))) float f32x4;

typedef __attribute__((address_space(1))) const void* as1cv;
typedef __attribute__((address_space(3))) void* as3v;

#define GLDS16(g, l) __builtin_amdgcn_global_load_lds((as1cv)(g), (as3v)(l), 16, 0, 0)

// round-to-nearest-even fp32 -> bf16 (inputs are finite randn; no NaN handling needed)
__device__ inline unsigned short f2bf(float x) {
  union { float f; unsigned u; } c; c.f = x;
  unsigned u = c.u;
  return (unsigned short)((u + 0x7fffu + ((u >> 16) & 1u)) >> 16);
}

__device__ inline short8 pack8(float4 a, float4 b) {
  short8 s;
  s[0] = (short)f2bf(a.x); s[1] = (short)f2bf(a.y);
  s[2] = (short)f2bf(a.z); s[3] = (short)f2bf(a.w);
  s[4] = (short)f2bf(b.x); s[5] = (short)f2bf(b.y);
  s[6] = (short)f2bf(b.z); s[7] = (short)f2bf(b.w);
  return s;
}

// ---------------- convert kernels (fp32 -> bf16 in workspace) ----------------

__global__ __launch_bounds__(256) void conv_a_kernel(const float* __restrict__ in,
                                                     unsigned short* __restrict__ out) {
  const size_t n8 = (size_t)M_DIM * K_DIM / 8;
  const size_t stride = (size_t)gridDim.x * blockDim.x;
  for (size_t i = (size_t)blockIdx.x * blockDim.x + threadIdx.x; i < n8; i += stride) {
    const float4* p = (const float4*)(in + i * 8);
    float4 v0 = p[0], v1 = p[1];
    *(short8*)(out + i * 8) = pack8(v0, v1);
  }
}

// B is padded to N_PAD rows; pad rows are zero-filled so the GEMM needs no guards.
__global__ __launch_bounds__(256) void conv_b_kernel(const float* __restrict__ in,
                                                     unsigned short* __restrict__ out) {
  const size_t n8 = (size_t)N_PAD * K_DIM / 8;
  const size_t stride = (size_t)gridDim.x * blockDim.x;
  const size_t k8 = K_DIM / 8;  // 4000
  for (size_t i = (size_t)blockIdx.x * blockDim.x + threadIdx.x; i < n8; i += stride) {
    const size_t row = i / k8;
    short8 s = {0, 0, 0, 0, 0, 0, 0, 0};
    if (row < N_DIM) {
      const float4* p = (const float4*)(in + i * 8);
      float4 v0 = p[0], v1 = p[1];
      s = pack8(v0, v1);
    }
    *(short8*)(out + i * 8) = s;
  }
}

// ---------------- MFMA compute core (shared by both GEMM modes) ----------------

__device__ inline void mfma_tile(const unsigned short* As, const unsigned short* Bs,
                                 f32x4 acc[4][4], int lane, int wr, int wc) {
  const int ar = lane & 15;
  const int ko = (lane >> 4) * 8;
  #pragma unroll
  for (int kk = 0; kk < BK / 32; ++kk) {
    short8 af[4], bf[4];
    #pragma unroll
    for (int m = 0; m < 4; ++m)
      af[m] = *(const short8*)&As[(wr * 64 + m * 16 + ar) * BK + kk * 32 + ko];
    #pragma unroll
    for (int n = 0; n < 4; ++n)
      bf[n] = *(const short8*)&Bs[(wc * 64 + n * 16 + ar) * BK + kk * 32 + ko];
    #pragma unroll
    for (int m = 0; m < 4; ++m)
      #pragma unroll
      for (int n = 0; n < 4; ++n)
        acc[m][n] = __builtin_amdgcn_mfma_f32_16x16x32_bf16(af[m], bf[n], acc[m][n], 0, 0, 0);
  }
}

// MODE 0: inputs are bf16 (workspace), staged via global_load_lds width=16.
// MODE 1: inputs are fp32 (original), reg-staged + cvt + ds_write_b128.
template<int MODE>
__global__ __launch_bounds__(256, 2)
void gemm_kernel(const void* __restrict__ Ap, const void* __restrict__ Bp,
                 float* __restrict__ C) {
  __shared__ __align__(16) unsigned short As[BM * BK];
  __shared__ __align__(16) unsigned short Bs[BN * BK];

  const int bid = blockIdx.x;
  // XCD-chunked swizzle (bijective: NWG % 8 == 0); tm fastest so 16 consecutive
  // logical tiles share one B panel (B streams from HBM once, A lives in LLC).
  const int wg = (bid & 7) * (NWG / 8) + (bid >> 3);
  const int tm = wg % NTM;
  const int tn = wg / NTM;
  const int tid = threadIdx.x;
  const int lane = tid & 63;
  const int w = tid >> 6;        // wave 0..3
  const int wr = w >> 1;         // 2x2 wave grid, each wave owns 64x64 output
  const int wc = w & 1;

  f32x4 acc[4][4];
  const f32x4 zero4 = {0.f, 0.f, 0.f, 0.f};
  #pragma unroll
  for (int i = 0; i < 4; ++i)
    #pragma unroll
    for (int j = 0; j < 4; ++j)
      acc[i][j] = zero4;

  if (MODE == 0) {
    const unsigned short* A = (const unsigned short*)Ap;
    const unsigned short* B = (const unsigned short*)Bp;
    const int lrow = lane >> 3;  // 8 rows per 1KiB global_load_lds
    const int lc16 = lane & 7;   // 16B chunk within a 128B row
    const unsigned short* ag = A + (size_t)(tm * BM + w * 32 + lrow) * K_DIM + lc16 * 8;
    const unsigned short* bg = B + (size_t)(tn * BN + w * 32 + lrow) * K_DIM + lc16 * 8;
    for (int kt = 0; kt < K_DIM / BK; ++kt) {
      #pragma unroll
      for (int i = 0; i < 4; ++i) {
        GLDS16(ag + (size_t)(i * 8) * K_DIM, &As[(w * 32 + i * 8) * BK]);
        GLDS16(bg + (size_t)(i * 8) * K_DIM, &Bs[(w * 32 + i * 8) * BK]);
      }
      ag += BK; bg += BK;
      __syncthreads();               // drains vmcnt: LDS tiles ready
      mfma_tile(As, Bs, acc, lane, wr, wc);
      __syncthreads();               // compute done before next overwrite
    }
  } else {
    const float* A = (const float*)Ap;
    const float* B = (const float*)Bp;
    for (int kt = 0; kt < K_DIM / BK; ++kt) {
      const int k0 = kt * BK;
      #pragma unroll
      for (int r = 0; r < 4; ++r) {
        const int f0 = r * 512 + tid * 2;   // float4 index, 0..2047
        const int row = f0 >> 4;            // 16 float4 per 64-col row
        const int c4 = f0 & 15;             // even
        const float* ga = A + (size_t)(tm * BM + row) * K_DIM + k0 + c4 * 4;
        float4 v0 = *(const float4*)ga;
        float4 v1 = *(const float4*)(ga + 4);
        *(short8*)&As[row * BK + c4 * 4] = pack8(v0, v1);
      }
      #pragma unroll
      for (int r = 0; r < 4; ++r) {
        const int f0 = r * 512 + tid * 2;
        const int row = f0 >> 4;
        const int c4 = f0 & 15;
        const int grow = tn * BN + row;
        short8 s = {0, 0, 0, 0, 0, 0, 0, 0};
        if (grow < N_DIM) {
          const float* gb = B + (size_t)grow * K_DIM + k0 + c4 * 4;
          float4 v0 = *(const float4*)gb;
          float4 v1 = *(const float4*)(gb + 4);
          s = pack8(v0, v1);
        }
        *(short8*)&Bs[row * BK + c4 * 4] = s;
      }
      __syncthreads();
      mfma_tile(As, Bs, acc, lane, wr, wc);
      __syncthreads();
    }
  }

  // C/D layout (16x16x32): col = lane&15, row = (lane>>4)*4 + j  [m89-verified]
  const int crow0 = tm * BM + wr * 64 + (lane >> 4) * 4;
  const int ccol0 = tn * BN + wc * 64 + (lane & 15);
  #pragma unroll
  for (int m = 0; m < 4; ++m) {
    #pragma unroll
    for (int n = 0; n < 4; ++n) {
      const int col = ccol0 + n * 16;
      if (col < N_DIM) {
        float* cp = C + (size_t)(crow0 + m * 16) * N_DIM + col;
        #pragma unroll
        for (int j = 0; j < 4; ++j)
          cp[(size_t)j * N_DIM] = acc[m][n][j];
      }
    }
  }
}

// ---------------- launch ----------------

extern "C" void kernel_launch(void* const* d_in, const int* in_sizes, int n_in,
                              void* d_out, int out_size, void* d_ws, size_t ws_size,
                              hipStream_t stream) {
  const float* A = (const float*)d_in[0];   // teacher_logits [2048][32000] fp32
  const float* B = (const float*)d_in[1];   // projection   [25000][32000] fp32
  float* C = (float*)d_out;                 // [2048][25000] fp32

  const size_t needA = (size_t)M_DIM * K_DIM * 2;   // 131,072,000 B
  const size_t needB = (size_t)N_PAD * K_DIM * 2;   // 1,605,632,000 B

  if (ws_size >= needA + needB) {
    unsigned short* wsA = (unsigned short*)d_ws;
    unsigned short* wsB = wsA + (size_t)M_DIM * K_DIM;
    conv_a_kernel<<<2048, 256, 0, stream>>>(A, wsA);
    conv_b_kernel<<<2048, 256, 0, stream>>>(B, wsB);
    gemm_kernel<0><<<NWG, 256, 0, stream>>>((const void*)wsA, (const void*)wsB, C);
  } else {
    gemm_kernel<1><<<NWG, 256, 0, stream>>>((const void*)A, (const void*)B, C);
  }
}

// Round 2
// 4318.288 us; speedup vs baseline: 1.1944x; 1.1944x over previous
//
#include <hip/hip_runtime.h>
#include <hip/hip_bf16.h>
#include <stdint.h>

#define M_DIM 2048
#define N_DIM 25000
#define K_DIM 32000
#define N_PAD 25088            // 98 * 256
#define NT_K  500              // K_DIM / 64

typedef __attribute__((ext_vector_type(8))) short short8;
typedef __attribute__((ext_vector_type(4))) float f32x4;

typedef __attribute__((address_space(1))) const void* as1cv;
typedef __attribute__((address_space(3))) void* as3v;
#define GLDS16(g, l) __builtin_amdgcn_global_load_lds((as1cv)(g), (as3v)(l), 16, 0, 0)

// round-to-nearest-even fp32 -> bf16
__device__ inline unsigned short f2bf(float x) {
  union { float f; unsigned u; } c; c.f = x;
  unsigned u = c.u;
  return (unsigned short)((u + 0x7fffu + ((u >> 16) & 1u)) >> 16);
}

__device__ inline short8 pack8(float4 a, float4 b) {
  short8 s;
  s[0] = (short)f2bf(a.x); s[1] = (short)f2bf(a.y);
  s[2] = (short)f2bf(a.z); s[3] = (short)f2bf(a.w);
  s[4] = (short)f2bf(b.x); s[5] = (short)f2bf(b.y);
  s[6] = (short)f2bf(b.z); s[7] = (short)f2bf(b.w);
  return s;
}

// ---------------- convert kernels (fp32 -> bf16 in workspace) ----------------

__global__ __launch_bounds__(256) void conv_a_kernel(const float* __restrict__ in,
                                                     unsigned short* __restrict__ out) {
  const size_t n8 = (size_t)M_DIM * K_DIM / 8;
  const size_t stride = (size_t)gridDim.x * blockDim.x;
  for (size_t i = (size_t)blockIdx.x * blockDim.x + threadIdx.x; i < n8; i += stride) {
    const float4* p = (const float4*)(in + i * 8);
    float4 v0 = p[0], v1 = p[1];
    *(short8*)(out + i * 8) = pack8(v0, v1);
  }
}

__global__ __launch_bounds__(256) void conv_b_kernel(const float* __restrict__ in,
                                                     unsigned short* __restrict__ out) {
  const size_t n8 = (size_t)N_PAD * K_DIM / 8;
  const size_t stride = (size_t)gridDim.x * blockDim.x;
  const size_t k8 = K_DIM / 8;  // 4000
  for (size_t i = (size_t)blockIdx.x * blockDim.x + threadIdx.x; i < n8; i += stride) {
    const size_t row = i / k8;
    short8 s = {0, 0, 0, 0, 0, 0, 0, 0};
    if (row < N_DIM) {
      const float4* p = (const float4*)(in + i * 8);
      float4 v0 = p[0], v1 = p[1];
      s = pack8(v0, v1);
    }
    *(short8*)(out + i * 8) = s;
  }
}

// ---------------- 256x256 8-phase GEMM (T1+T2+T3+T4+T5) ----------------
// LDS layout per buffer: A tile 256x64 bf16 as 32 subtiles of 16 rows x 32 cols
// (1024 B each, = one wave global_load_lds issue), then B tile same. 2 buffers.
// Swizzle within subtile: 16B-chunk c' = c ^ ((row>>1)&3) -- applied to the
// pre-swizzled GLOBAL source on stage and to the ds_read address (rule 21).

#define BARR  __builtin_amdgcn_s_barrier()
#define LGKM0 do { asm volatile("s_waitcnt lgkmcnt(0)" ::: "memory"); \
                   __builtin_amdgcn_sched_barrier(0); } while (0)
#define VMC4  asm volatile("s_waitcnt vmcnt(4)" ::: "memory")
#define VMC0  asm volatile("s_waitcnt vmcnt(0)" ::: "memory")
#define PRIO1 __builtin_amdgcn_s_setprio(1)
#define PRIO0 __builtin_amdgcn_s_setprio(0)

#define READ_AF(P, MH) { _Pragma("unroll") for (int m2_ = 0; m2_ < 4; ++m2_) { \
  _Pragma("unroll") for (int kk_ = 0; kk_ < 2; ++kk_) \
    af[m2_][kk_] = *(const short8*)(rdA##P + (((MH) * 4 + m2_) * 2 + kk_) * 512); } }

#define READ_BF(P, NH) { _Pragma("unroll") for (int n2_ = 0; n2_ < 2; ++n2_) { \
  _Pragma("unroll") for (int kk_ = 0; kk_ < 2; ++kk_) \
    bf[NH][n2_][kk_] = *(const short8*)(rdB##P + (((NH) * 2 + n2_) * 2 + kk_) * 512); } }

#define MFMA_Q(MH, NH) { _Pragma("unroll") for (int kk_ = 0; kk_ < 2; ++kk_) { \
  _Pragma("unroll") for (int m2_ = 0; m2_ < 4; ++m2_) { \
  _Pragma("unroll") for (int n2_ = 0; n2_ < 2; ++n2_) \
    acc[(MH)*4+m2_][(NH)*2+n2_] = __builtin_amdgcn_mfma_f32_16x16x32_bf16( \
        af[m2_][kk_], bf[NH][n2_][kk_], acc[(MH)*4+m2_][(NH)*2+n2_], 0, 0, 0); } } }

#define STAGE_A(P, KT, H) do { \
  const unsigned short* s_ = agp + (size_t)(H) * (128 * (size_t)K_DIM) + (size_t)(KT) * 64; \
  GLDS16(s_,      stA##P + (H) * 8192); \
  GLDS16(s_ + 32, stA##P + (H) * 8192 + 512); } while (0)

#define STAGE_B(P, KT, H) do { \
  const unsigned short* s_ = bgp + (size_t)(H) * (128 * (size_t)K_DIM) + (size_t)(KT) * 64; \
  GLDS16(s_,      stB##P + (H) * 8192); \
  GLDS16(s_ + 32, stB##P + (H) * 8192 + 512); } while (0)

__global__ __launch_bounds__(512, 2)
void gemm8_kernel(const unsigned short* __restrict__ A, const unsigned short* __restrict__ B,
                  float* __restrict__ C) {
  extern __shared__ __align__(16) unsigned short lds[];  // 131072 B
  unsigned short* const LA0 = lds;            // [0,      16384) ushorts
  unsigned short* const LB0 = lds + 16384;    // [16384,  32768)
  unsigned short* const LA1 = lds + 32768;    // [32768,  49152)
  unsigned short* const LB1 = lds + 49152;    // [49152,  65536)

  const int bid = blockIdx.x;
  const int wg = (bid & 7) * 98 + (bid >> 3);   // bijective XCD chunking (784 % 8 == 0)
  const int tm = wg & 7;                        // M tile 0..7 (fastest: shares B panel)
  const int tn = wg >> 3;                       // N tile 0..97
  const int tid = threadIdx.x;
  const int lane = tid & 63;
  const int w = tid >> 6;        // wave 0..7
  const int wm = w >> 2;         // 2 waves in M (128 rows each)
  const int wn = w & 3;          // 4 waves in N (64 cols each)

  // ds_read fragment addressing: subtile = 16 rows x 32 cols; lane row = lane&15,
  // logical 16B chunk c = lane>>4, swizzled position c' = c ^ ((row>>1)&3).
  const int laneoff = (lane & 15) * 32 + (((lane >> 4) ^ ((lane >> 1) & 3)) << 3);
  const unsigned short* const rdA0 = LA0 + wm * (16 * 512) + laneoff;
  const unsigned short* const rdA1 = LA1 + wm * (16 * 512) + laneoff;
  const int bsub = (wn >> 1) * 16 + (wn & 1) * 8;
  const unsigned short* const rdB0 = LB0 + bsub * 512 + laneoff;
  const unsigned short* const rdB1 = LB1 + bsub * 512 + laneoff;

  // staging: wave w stages rowgrp w (16 rows) of each 128-row half (2 subtiles).
  // lane l -> row w*16 + (l>>2), LDS position chunk l&3; inverse-swizzled global
  // source chunk = (l&3) ^ ((l>>3)&3)   [(row>>1)&3 = (l>>3)&3].
  const int srow = w * 16 + (lane >> 2);
  const int schunk = ((lane & 3) ^ ((lane >> 3) & 3)) * 8;
  const unsigned short* const agp = A + (size_t)(tm * 256 + srow) * K_DIM + schunk;
  const unsigned short* const bgp = B + (size_t)(tn * 256 + srow) * K_DIM + schunk;
  unsigned short* const stA0 = LA0 + w * 1024;
  unsigned short* const stA1 = LA1 + w * 1024;
  unsigned short* const stB0 = LB0 + w * 1024;
  unsigned short* const stB1 = LB1 + w * 1024;

  f32x4 acc[8][4];
  const f32x4 z4 = {0.f, 0.f, 0.f, 0.f};
  #pragma unroll
  for (int i = 0; i < 8; ++i)
    #pragma unroll
    for (int j = 0; j < 4; ++j) acc[i][j] = z4;

  short8 af[4][2];      // current mh: 4 m-frags x 2 k-slices
  short8 bf[2][2][2];   // [nh][n'][kk], both nh sets stay live

  // ---- prologue: tile0 fully + Bh(1); wait tile0 landed (<=4 outstanding) ----
  STAGE_B(0, 0, 0); STAGE_B(0, 0, 1);
  STAGE_A(0, 0, 0); STAGE_A(0, 0, 1);
  STAGE_B(1, 1, 0); STAGE_B(1, 1, 1);
  VMC4; BARR;

  // ---- main loop: tiles (t, t+1) per iteration; t = 0,2,...,496 ----
  #pragma unroll 1
  for (int it = 0; it < 249; ++it) {
    const int t = 2 * it;
    // P1 (tile t, q0): new A(mh0) + B(nh0); stage Ah0(t+1)
    READ_AF(0, 0); READ_BF(0, 0); STAGE_A(1, t + 1, 0);
    BARR; LGKM0; PRIO1; MFMA_Q(0, 0); PRIO0; BARR;
    // P2 (q1): new B(nh1); stage Ah1(t+1)
    READ_BF(0, 1); STAGE_A(1, t + 1, 1);
    BARR; LGKM0; PRIO1; MFMA_Q(0, 1); PRIO0; BARR;
    // P3 (q2): new A(mh1); stage Bh0(t+2)  [B(t) last read at P2]
    READ_AF(0, 1); STAGE_B(0, t + 2, 0);
    BARR; LGKM0; PRIO1; MFMA_Q(1, 1); PRIO0; BARR;
    // P4 (q3): no reads; stage Bh1(t+2); counted wait -> tile t+1 ready
    STAGE_B(0, t + 2, 1);
    BARR; PRIO1; MFMA_Q(1, 0); PRIO0; VMC4; BARR;
    // P5 (tile t+1, q0): stage Ah0(t+2)  [A(t) last read at P3]
    READ_AF(1, 0); READ_BF(1, 0); STAGE_A(0, t + 2, 0);
    BARR; LGKM0; PRIO1; MFMA_Q(0, 0); PRIO0; BARR;
    // P6 (q1): stage Ah1(t+2)
    READ_BF(1, 1); STAGE_A(0, t + 2, 1);
    BARR; LGKM0; PRIO1; MFMA_Q(0, 1); PRIO0; BARR;
    // P7 (q2): stage Bh0(t+3)  [B(t+1) last read at P6]
    READ_AF(1, 1); STAGE_B(1, t + 3, 0);
    BARR; LGKM0; PRIO1; MFMA_Q(1, 1); PRIO0; BARR;
    // P8 (q3): stage Bh1(t+3); counted wait -> tile t+2 ready
    STAGE_B(1, t + 3, 1);
    BARR; PRIO1; MFMA_Q(1, 0); PRIO0; VMC4; BARR;
  }

  // ---- tail: tile 498 (stages only Ah(499)), then tile 499 ----
  READ_AF(0, 0); READ_BF(0, 0); STAGE_A(1, 499, 0);
  BARR; LGKM0; PRIO1; MFMA_Q(0, 0); PRIO0; BARR;
  READ_BF(0, 1); STAGE_A(1, 499, 1);
  BARR; LGKM0; PRIO1; MFMA_Q(0, 1); PRIO0; BARR;
  READ_AF(0, 1);
  BARR; LGKM0; PRIO1; MFMA_Q(1, 1); PRIO0; BARR;
  BARR; PRIO1; MFMA_Q(1, 0); PRIO0; VMC0; BARR;
  READ_AF(1, 0); READ_BF(1, 0);
  BARR; LGKM0; PRIO1; MFMA_Q(0, 0); PRIO0; BARR;
  READ_BF(1, 1);
  BARR; LGKM0; PRIO1; MFMA_Q(0, 1); PRIO0; BARR;
  READ_AF(1, 1);
  BARR; LGKM0; PRIO1; MFMA_Q(1, 1); PRIO0; BARR;
  PRIO1; MFMA_Q(1, 0); PRIO0;

  // ---- epilogue: C/D layout col=lane&15, row=(lane>>4)*4+j [m89-verified] ----
  const int crow0 = tm * 256 + wm * 128 + (lane >> 4) * 4;
  const int ccol0 = tn * 256 + wn * 64 + (lane & 15);
  #pragma unroll
  for (int m = 0; m < 8; ++m) {
    #pragma unroll
    for (int n = 0; n < 4; ++n) {
      const int col = ccol0 + n * 16;
      if (col < N_DIM) {
        float* cp = C + (size_t)(crow0 + m * 16) * N_DIM + col;
        #pragma unroll
        for (int j = 0; j < 4; ++j)
          cp[(size_t)j * N_DIM] = acc[m][n][j];
      }
    }
  }
}

// ---------------- fallback (r1-validated 128^2 reg-staged fp32 path) ----------------

__device__ inline void mfma_tile_fb(const unsigned short* As, const unsigned short* Bs,
                                    f32x4 acc[4][4], int lane, int wr, int wc) {
  const int ar = lane & 15;
  const int ko = (lane >> 4) * 8;
  #pragma unroll
  for (int kk = 0; kk < 2; ++kk) {
    short8 a2[4], b2[4];
    #pragma unroll
    for (int m = 0; m < 4; ++m)
      a2[m] = *(const short8*)&As[(wr * 64 + m * 16 + ar) * 64 + kk * 32 + ko];
    #pragma unroll
    for (int n = 0; n < 4; ++n)
      b2[n] = *(const short8*)&Bs[(wc * 64 + n * 16 + ar) * 64 + kk * 32 + ko];
    #pragma unroll
    for (int m = 0; m < 4; ++m)
      #pragma unroll
      for (int n = 0; n < 4; ++n)
        acc[m][n] = __builtin_amdgcn_mfma_f32_16x16x32_bf16(a2[m], b2[n], acc[m][n], 0, 0, 0);
  }
}

__global__ __launch_bounds__(256, 2)
void gemm_fb_kernel(const float* __restrict__ A, const float* __restrict__ B,
                    float* __restrict__ C) {
  __shared__ __align__(16) unsigned short As[128 * 64];
  __shared__ __align__(16) unsigned short Bs[128 * 64];
  const int bid = blockIdx.x;
  const int wg = (bid & 7) * (3136 / 8) + (bid >> 3);
  const int tm = wg % 16;
  const int tn = wg / 16;
  const int tid = threadIdx.x;
  const int lane = tid & 63;
  const int w = tid >> 6;
  const int wr = w >> 1;
  const int wc = w & 1;
  f32x4 acc[4][4];
  const f32x4 z4 = {0.f, 0.f, 0.f, 0.f};
  #pragma unroll
  for (int i = 0; i < 4; ++i)
    #pragma unroll
    for (int j = 0; j < 4; ++j) acc[i][j] = z4;
  for (int kt = 0; kt < K_DIM / 64; ++kt) {
    const int k0 = kt * 64;
    #pragma unroll
    for (int r = 0; r < 4; ++r) {
      const int f0 = r * 512 + tid * 2;
      const int row = f0 >> 4;
      const int c4 = f0 & 15;
      const float* ga = A + (size_t)(tm * 128 + row) * K_DIM + k0 + c4 * 4;
      float4 v0 = *(const float4*)ga;
      float4 v1 = *(const float4*)(ga + 4);
      *(short8*)&As[row * 64 + c4 * 4] = pack8(v0, v1);
    }
    #pragma unroll
    for (int r = 0; r < 4; ++r) {
      const int f0 = r * 512 + tid * 2;
      const int row = f0 >> 4;
      const int c4 = f0 & 15;
      const int grow = tn * 128 + row;
      short8 s = {0, 0, 0, 0, 0, 0, 0, 0};
      if (grow < N_DIM) {
        const float* gb = B + (size_t)grow * K_DIM + k0 + c4 * 4;
        float4 v0 = *(const float4*)gb;
        float4 v1 = *(const float4*)(gb + 4);
        s = pack8(v0, v1);
      }
      *(short8*)&Bs[row * 64 + c4 * 4] = s;
    }
    __syncthreads();
    mfma_tile_fb(As, Bs, acc, lane, wr, wc);
    __syncthreads();
  }
  const int crow0 = tm * 128 + wr * 64 + (lane >> 4) * 4;
  const int ccol0 = tn * 128 + wc * 64 + (lane & 15);
  #pragma unroll
  for (int m = 0; m < 4; ++m) {
    #pragma unroll
    for (int n = 0; n < 4; ++n) {
      const int col = ccol0 + n * 16;
      if (col < N_DIM) {
        float* cp = C + (size_t)(crow0 + m * 16) * N_DIM + col;
        #pragma unroll
        for (int j = 0; j < 4; ++j)
          cp[(size_t)j * N_DIM] = acc[m][n][j];
      }
    }
  }
}

// ---------------- launch ----------------

extern "C" void kernel_launch(void* const* d_in, const int* in_sizes, int n_in,
                              void* d_out, int out_size, void* d_ws, size_t ws_size,
                              hipStream_t stream) {
  const float* A = (const float*)d_in[0];   // teacher_logits [2048][32000] fp32
  const float* B = (const float*)d_in[1];   // projection   [25000][32000] fp32
  float* C = (float*)d_out;                 // [2048][25000] fp32

  const size_t needA = (size_t)M_DIM * K_DIM * 2;
  const size_t needB = (size_t)N_PAD * K_DIM * 2;

  if (ws_size >= needA + needB) {
    unsigned short* wsA = (unsigned short*)d_ws;
    unsigned short* wsB = wsA + (size_t)M_DIM * K_DIM;
    conv_a_kernel<<<2048, 256, 0, stream>>>(A, wsA);
    conv_b_kernel<<<2048, 256, 0, stream>>>(B, wsB);
    (void)hipFuncSetAttribute((const void*)gemm8_kernel,
                              hipFuncAttributeMaxDynamicSharedMemorySize, 131072);
    gemm8_kernel<<<784, 512, 131072, stream>>>(wsA, wsB, C);
  } else {
    gemm_fb_kernel<<<3136, 256, 0, stream>>>(A, B, C);
  }
}